// Round 6
// baseline (190.770 us; speedup 1.0000x reference)
//
#include <hip/hip_runtime.h>
#include <math.h>

// Problem constants (fixed by reference)
//  B=128, N=32, M=64, OBS=128, ACT=16, D_QK=128, D_AV=64, F_IN=144, H=64
// Outputs concatenated: value [B,32,32] @0, ret_weight [B,32,32] @131072,
// weight_other [B,32,64] @262144.
//
// Workspace (floats), 2,129,920 floats = 8.125 MB:
#define WS_WQK     0         // [128][128]
#define WS_WQKO    16384     // [128][128]
#define WS_AVA     32768     // [B][32][64]  scratch: tanh(oa@W_av)
#define WS_DELTA   294912    // [B][32][64]  scratch: tanh(op@W_av)-avA
#define WS_AVO     557056    // [B][64][64]  scratch: tanh(oao@W_avo)
#define WS_AVAPRJ  1081344   // [B][32][64]  avA @ W_f1a
#define WS_DPROJ   1343488   // [B][32][64]  delta @ W_f1a
#define WS_AVOPRJ  1605632   // [B][64][64]  avO @ W_f1b

#define INV_SQRT_DK 0.08838834764831845f  // 1/sqrt(128)

__device__ __forceinline__ float dot4(float4 a, float4 b) {
  return a.x*b.x + a.y*b.y + a.z*b.z + a.w*b.w;
}

// ---------------------------------------------------------------------------
// K1: independent pre-work. grid 416:
//   [0,32)    Wqk / Wqko fusion tiles (32x32 out each) — only LDS user
//   [32,160)  per b: avA/delta -> ws -> avAproj, dproj (no LDS)
//   [160,416) per (b, m-half): avO -> ws -> avOproj   (no LDS)
// ---------------------------------------------------------------------------
__global__ __launch_bounds__(256, 4) void k1_pre(
    const float* __restrict__ g_states, const float* __restrict__ g_pol,
    const float* __restrict__ g_act, const float* __restrict__ g_so,
    const float* __restrict__ g_ao,
    const float* __restrict__ Wq, const float* __restrict__ Wk,
    const float* __restrict__ Wqo, const float* __restrict__ Wko,
    const float* __restrict__ W_av, const float* __restrict__ W_avo,
    const float* __restrict__ W_f1, float* __restrict__ ws)
{
  __shared__ __align__(16) float pool[8448];   // 33 KB (fusion branch only)
  const int t = threadIdx.x;
  int blk = blockIdx.x;

  if (blk < 32) {
    // ---- weight fusion: Wqk[c][e] = sum_d Wq[c,d]*Wk[e,d] ----------------
    const float* A; const float* Bm; float* O;
    if (blk < 16) { A = Wq;  Bm = Wk;  O = ws + WS_WQK; }
    else          { A = Wqo; Bm = Wko; O = ws + WS_WQKO; blk -= 16; }
    const int tr = (blk >> 2) << 5;
    const int tc = (blk & 3) << 5;
    float* sA = pool;                 // [32][132]
    float* sB = pool + 4224;          // [32][132]
    const float4* a4 = (const float4*)(A + tr * 128);
    const float4* b4 = (const float4*)(Bm + tc * 128);
    #pragma unroll
    for (int u = 0; u < 4; ++u) {
      int f = t + u * 256;
      int r = f >> 5, c4 = f & 31;
      *(float4*)(sA + r*132 + c4*4) = a4[f];
      *(float4*)(sB + r*132 + c4*4) = b4[f];
    }
    __syncthreads();
    const int e = t & 31, cl0 = t >> 5;
    float acc[4] = {0,0,0,0};
    #pragma unroll 4
    for (int d4 = 0; d4 < 32; ++d4) {
      float4 bv = *(const float4*)(sB + e*132 + d4*4);
      #pragma unroll
      for (int rr = 0; rr < 4; ++rr) {
        float4 av = *(const float4*)(sA + (cl0 + rr*8)*132 + d4*4);
        acc[rr] += dot4(av, bv);
      }
    }
    #pragma unroll
    for (int rr = 0; rr < 4; ++rr)
      O[(tr + cl0 + rr*8)*128 + tc + e] = acc[rr];
    return;
  }
  blk -= 32;

  if (blk < 128) {
    // ---- per b: avA + delta (to ws) then avAproj + dproj -----------------
    const int b = blk;
    const int rg = t >> 6, lane = t & 63;
    // phase A: wave rg handles rows rg*8..rg*8+7; lane = d column
    {
      const float* gs = g_states + b*4096 + rg*8*128;
      const float* ga = g_act + b*512 + rg*8*16;
      const float* gp = g_pol + b*512 + rg*8*16;
      float accS[8] = {0,0,0,0,0,0,0,0};
      #pragma unroll 4
      for (int c4 = 0; c4 < 32; ++c4) {
        const float w0 = W_av[(c4*4+0)*64 + lane];
        const float w1 = W_av[(c4*4+1)*64 + lane];
        const float w2 = W_av[(c4*4+2)*64 + lane];
        const float w3 = W_av[(c4*4+3)*64 + lane];
        #pragma unroll
        for (int r = 0; r < 8; ++r) {
          float4 sv = *(const float4*)(gs + r*128 + c4*4);   // broadcast
          accS[r] += sv.x*w0 + sv.y*w1 + sv.z*w2 + sv.w*w3;
        }
      }
      float accA[8], accP[8];
      #pragma unroll
      for (int r = 0; r < 8; ++r) { accA[r] = accS[r]; accP[r] = accS[r]; }
      #pragma unroll
      for (int c4 = 0; c4 < 4; ++c4) {
        const float w0 = W_av[(128 + c4*4+0)*64 + lane];
        const float w1 = W_av[(128 + c4*4+1)*64 + lane];
        const float w2 = W_av[(128 + c4*4+2)*64 + lane];
        const float w3 = W_av[(128 + c4*4+3)*64 + lane];
        #pragma unroll
        for (int r = 0; r < 8; ++r) {
          float4 sa = *(const float4*)(ga + r*16 + c4*4);
          float4 sp = *(const float4*)(gp + r*16 + c4*4);
          accA[r] += sa.x*w0 + sa.y*w1 + sa.z*w2 + sa.w*w3;
          accP[r] += sp.x*w0 + sp.y*w1 + sp.z*w2 + sp.w*w3;
        }
      }
      #pragma unroll
      for (int r = 0; r < 8; ++r) {
        float va = tanhf(accA[r]);
        float dl = tanhf(accP[r]) - va;
        ws[WS_AVA   + b*2048 + (rg*8 + r)*64 + lane] = va;   // coalesced
        ws[WS_DELTA + b*2048 + (rg*8 + r)*64 + lane] = dl;
      }
    }
    __syncthreads();   // drains vmcnt; ws writes visible via L2
    // proj: wave = (array, 16-row half); lane = h column
    {
      const int arr = rg & 1, j0 = (rg >> 1) * 16;
      const float* src = ws + (arr ? WS_DELTA : WS_AVA) + b*2048 + j0*64;
      float*       dst = ws + (arr ? WS_DPROJ : WS_AVAPRJ) + b*2048 + j0*64;
      float acc[16];
      #pragma unroll
      for (int q = 0; q < 16; ++q) acc[q] = 0.f;
      #pragma unroll 2
      for (int d4 = 0; d4 < 16; ++d4) {
        const float w0 = W_f1[(d4*4+0)*64 + lane];
        const float w1 = W_f1[(d4*4+1)*64 + lane];
        const float w2 = W_f1[(d4*4+2)*64 + lane];
        const float w3 = W_f1[(d4*4+3)*64 + lane];
        #pragma unroll
        for (int q = 0; q < 16; ++q) {
          float4 dv = *(const float4*)(src + q*64 + d4*4);   // broadcast (L2)
          acc[q] += dv.x*w0 + dv.y*w1 + dv.z*w2 + dv.w*w3;
        }
      }
      #pragma unroll
      for (int q = 0; q < 16; ++q)
        dst[q*64 + lane] = acc[q];                            // coalesced
    }
    return;
  }
  blk -= 128;

  // ---- per (b, m-half32): avO (to ws) then avOproj -----------------------
  {
    const int b = blk >> 1, m0 = (blk & 1) << 5;
    const int rg = t >> 6, lane = t & 63;
    {
      const float* gso = g_so + (b*64 + m0 + rg*8) * 128;
      const float* gao = g_ao + (b*64 + m0 + rg*8) * 16;
      float acc[8] = {0,0,0,0,0,0,0,0};
      #pragma unroll 4
      for (int c4 = 0; c4 < 32; ++c4) {
        const float w0 = W_avo[(c4*4+0)*64 + lane];
        const float w1 = W_avo[(c4*4+1)*64 + lane];
        const float w2 = W_avo[(c4*4+2)*64 + lane];
        const float w3 = W_avo[(c4*4+3)*64 + lane];
        #pragma unroll
        for (int r = 0; r < 8; ++r) {
          float4 sv = *(const float4*)(gso + r*128 + c4*4);  // broadcast
          acc[r] += sv.x*w0 + sv.y*w1 + sv.z*w2 + sv.w*w3;
        }
      }
      #pragma unroll
      for (int c4 = 0; c4 < 4; ++c4) {
        const float w0 = W_avo[(128 + c4*4+0)*64 + lane];
        const float w1 = W_avo[(128 + c4*4+1)*64 + lane];
        const float w2 = W_avo[(128 + c4*4+2)*64 + lane];
        const float w3 = W_avo[(128 + c4*4+3)*64 + lane];
        #pragma unroll
        for (int r = 0; r < 8; ++r) {
          float4 sv = *(const float4*)(gao + r*16 + c4*4);
          acc[r] += sv.x*w0 + sv.y*w1 + sv.z*w2 + sv.w*w3;
        }
      }
      #pragma unroll
      for (int r = 0; r < 8; ++r)
        ws[WS_AVO + b*4096 + (m0 + rg*8 + r)*64 + lane] = tanhf(acc[r]);
    }
    __syncthreads();
    {
      // avOproj rows j0..j0+7 (own wave's rows); Wf1b = W_f1 rows 64..127
      const int j0 = m0 + rg*8;
      const float* src = ws + WS_AVO + b*4096 + j0*64;
      float*       dst = ws + WS_AVOPRJ + b*4096 + j0*64;
      float acc[8] = {0,0,0,0,0,0,0,0};
      #pragma unroll 2
      for (int d4 = 0; d4 < 16; ++d4) {
        const float w0 = W_f1[(64 + d4*4+0)*64 + lane];
        const float w1 = W_f1[(64 + d4*4+1)*64 + lane];
        const float w2 = W_f1[(64 + d4*4+2)*64 + lane];
        const float w3 = W_f1[(64 + d4*4+3)*64 + lane];
        #pragma unroll
        for (int q = 0; q < 8; ++q) {
          float4 ov = *(const float4*)(src + q*64 + d4*4);   // broadcast (L2)
          acc[q] += ov.x*w0 + ov.y*w1 + ov.z*w2 + ov.w*w3;
        }
      }
      #pragma unroll
      for (int q = 0; q < 8; ++q)
        dst[q*64 + lane] = acc[q];                            // coalesced
    }
  }
}

// ---------------------------------------------------------------------------
// K2: main, per (b, i-octile). grid 512. LDS 3.6K floats = 14.3 KB.
// All large operands read directly from global (L1/L2-hot).
// ---------------------------------------------------------------------------
__global__ __launch_bounds__(256, 4) void k2_main(
    const float* __restrict__ g_states, const float* __restrict__ g_so,
    const float* __restrict__ ws, float* __restrict__ out,
    const float* __restrict__ W_f2)
{
  __shared__ __align__(16) float s_P[8*268];    // [8][268] P1|P2
  __shared__ __align__(16) float s_w[8*36];
  __shared__ __align__(16) float s_wo[8*68];
  __shared__ __align__(16) float s_base[8*68];
  __shared__ __align__(16) float s_wf2[64];

  const int t = threadIdx.x;
  const int b = blockIdx.x >> 2;
  const int i0 = (blockIdx.x & 3) << 3;

  if (t < 16) *(float4*)(s_wf2 + t*4) = ((const float4*)W_f2)[t];

  // ---- ph2: P = states[i0..+8] @ [Wqk|Wqko], register-resident -----------
  {
    const int wv = t >> 6, lane = t & 63;
    const int cg = wv*64 + lane;                 // col 0..255
    const float* Wp = (wv < 2) ? (ws + WS_WQK  + cg)
                               : (ws + WS_WQKO + cg - 128);
    const float* srow = g_states + b*4096 + i0*128;
    float acc[8] = {0,0,0,0,0,0,0,0};
    #pragma unroll 4
    for (int c4 = 0; c4 < 32; ++c4) {
      float4 sv[8];
      #pragma unroll
      for (int r = 0; r < 8; ++r)
        sv[r] = *(const float4*)(srow + r*128 + c4*4);   // broadcast
      #pragma unroll
      for (int kk = 0; kk < 4; ++kk) {
        float wvv = Wp[(c4*4 + kk)*128];                 // coalesced
        #pragma unroll
        for (int r = 0; r < 8; ++r)
          acc[r] += wvv * ((const float*)&sv[r])[kk];
      }
    }
    #pragma unroll
    for (int r = 0; r < 8; ++r)
      s_P[r*268 + cg] = acc[r];
  }
  __syncthreads();

  // ---- ph3: self scores + softmax; ph4: other scores (no barrier between)
  {
    const int r = t >> 5, j = t & 31;
    float acc = 0.f;
    #pragma unroll 8
    for (int e4 = 0; e4 < 32; ++e4) {
      float4 p4  = *(const float4*)(s_P + r*268 + e4*4);
      float4 st4 = *(const float4*)(g_states + b*4096 + j*128 + e4*4); // gather
      acc += dot4(p4, st4);
    }
    acc *= INV_SQRT_DK;
    float mx = acc;
    for (int off = 16; off; off >>= 1) mx = fmaxf(mx, __shfl_xor(mx, off, 32));
    float ev = __expf(acc - mx);
    float sum = ev;
    for (int off = 16; off; off >>= 1) sum += __shfl_xor(sum, off, 32);
    float wn = ev / sum;
    out[131072 + b*1024 + (i0 + r)*32 + j] = wn;
    s_w[r*36 + j] = wn;

    #pragma unroll
    for (int tt = 0; tt < 2; ++tt) {
      float a2 = 0.f;
      #pragma unroll 8
      for (int c4 = 0; c4 < 32; ++c4) {
        float4 p4  = *(const float4*)(s_P + r*268 + 128 + c4*4);
        float4 so4 = *(const float4*)(g_so + (b*64 + tt*32 + j)*128 + c4*4);
        a2 += dot4(p4, so4);
      }
      s_wo[r*68 + tt*32 + j] = a2 * INV_SQRT_DK;
    }
  }
  __syncthreads();

  // ---- ph6: softmax wo + write weight_other ------------------------------
  #pragma unroll
  for (int p = 0; p < 2; ++p) {
    const int r = (t >> 6) + (p << 2), l = t & 63;
    float v = s_wo[r*68 + l];
    float mx = v;
    for (int off = 32; off; off >>= 1) mx = fmaxf(mx, __shfl_xor(mx, off, 64));
    float ev = __expf(v - mx);
    float sum = ev;
    for (int off = 32; off; off >>= 1) sum += __shfl_xor(sum, off, 64);
    float wn = ev / sum;
    out[262144 + b*2048 + (i0 + r)*64 + l] = wn;
    s_wo[r*68 + l] = wn;
  }
  __syncthreads();

  // ---- ph7: base[i][h] = sum_k w[i,k]avAproj[k,h] + sum_m wo[i,m]avOproj[m,h]
  {
    const int g = t >> 6, h = t & 63;
    const int r0 = g*2, r1 = r0 + 1;
    const float* ap_ = ws + WS_AVAPRJ + b*2048 + h;
    const float* op_ = ws + WS_AVOPRJ + b*4096 + h;
    float a0 = 0.f, a1 = 0.f;
    #pragma unroll 2
    for (int k4 = 0; k4 < 8; ++k4) {
      float4 wa = *(const float4*)(s_w + r0*36 + k4*4);   // broadcast LDS
      float4 wb = *(const float4*)(s_w + r1*36 + k4*4);
      #pragma unroll
      for (int kk = 0; kk < 4; ++kk) {
        float pv = ap_[(k4*4 + kk)*64];                   // coalesced global
        a0 += ((const float*)&wa)[kk] * pv;
        a1 += ((const float*)&wb)[kk] * pv;
      }
    }
    #pragma unroll 2
    for (int m4 = 0; m4 < 16; ++m4) {
      float4 wa = *(const float4*)(s_wo + r0*68 + m4*4);
      float4 wb = *(const float4*)(s_wo + r1*68 + m4*4);
      #pragma unroll
      for (int kk = 0; kk < 4; ++kk) {
        float pv = op_[(m4*4 + kk)*64];                   // coalesced global
        a0 += ((const float*)&wa)[kk] * pv;
        a1 += ((const float*)&wb)[kk] * pv;
      }
    }
    s_base[r0*68 + h] = a0;
    s_base[r1*68 + h] = a1;
  }
  __syncthreads();

  // ---- ph9: value[i][j] = sum_h lrelu(base[i,h]+w[i,j]*dproj[j,h])*Wf2[h] -
  {
    const int i = t >> 5, j = t & 31;
    const float wij = s_w[i*36 + j];
    const float* dp = ws + WS_DPROJ + b*2048 + j*64;
    float acc = 0.f;
    #pragma unroll 4
    for (int hq = 0; hq < 16; ++hq) {
      float4 b4 = *(const float4*)(s_base + i*68 + hq*4);
      float4 d4 = *(const float4*)(dp + hq*4);            // gather global
      float4 f4 = *(const float4*)(s_wf2 + hq*4);
      float p0 = b4.x + wij*d4.x; p0 = p0 > 0.f ? p0 : 0.01f*p0;
      float p1 = b4.y + wij*d4.y; p1 = p1 > 0.f ? p1 : 0.01f*p1;
      float p2 = b4.z + wij*d4.z; p2 = p2 > 0.f ? p2 : 0.01f*p2;
      float p3 = b4.w + wij*d4.w; p3 = p3 > 0.f ? p3 : 0.01f*p3;
      acc += p0*f4.x + p1*f4.y + p2*f4.z + p3*f4.w;
    }
    out[b*1024 + (i0 + i)*32 + j] = acc;
  }
}

extern "C" void kernel_launch(void* const* d_in, const int* in_sizes, int n_in,
                              void* d_out, int out_size, void* d_ws, size_t ws_size,
                              hipStream_t stream) {
  const float* states        = (const float*)d_in[0];
  const float* policies      = (const float*)d_in[1];
  const float* actions       = (const float*)d_in[2];
  const float* states_other  = (const float*)d_in[3];
  const float* actions_other = (const float*)d_in[4];
  const float* W_key         = (const float*)d_in[5];
  const float* W_query       = (const float*)d_in[6];
  const float* W_av          = (const float*)d_in[7];
  const float* W_key_other   = (const float*)d_in[8];
  const float* W_query_other = (const float*)d_in[9];
  const float* W_av_other    = (const float*)d_in[10];
  const float* W_f1          = (const float*)d_in[11];
  const float* W_f2          = (const float*)d_in[12];
  float* out = (float*)d_out;
  float* ws  = (float*)d_ws;   // 8.125 MB used

  k1_pre<<<416, 256, 0, stream>>>(states, policies, actions, states_other,
                                  actions_other, W_query, W_key,
                                  W_query_other, W_key_other, W_av, W_av_other,
                                  W_f1, ws);
  k2_main<<<512, 256, 0, stream>>>(states, states_other, ws, out, W_f2);
}

// Round 7
// 169.606 us; speedup vs baseline: 1.1248x; 1.1248x over previous
//
#include <hip/hip_runtime.h>
#include <math.h>

// Problem constants (fixed by reference)
//  B=128, N=32, M=64, OBS=128, ACT=16, D_QK=128, D_AV=64, F_IN=144, H=64
// Outputs concatenated: value [B,32,32] @0, ret_weight [B,32,32] @131072,
// weight_other [B,32,64] @262144.
//
// Workspace (floats), 1,081,344 floats = 4.125 MB:
#define WS_WQK   0         // [128][128]
#define WS_WQKO  16384     // [128][128]
#define WS_AVA   32768     // [B][32][64]
#define WS_AVO   294912    // [B][64][64]
#define WS_DPROJ 819200    // [B][32][64]

#define INV_SQRT_DK 0.08838834764831845f  // 1/sqrt(128)

__device__ __forceinline__ float dot4(float4 a, float4 b) {
  return a.x*b.x + a.y*b.y + a.z*b.z + a.w*b.w;
}

// ---------------------------------------------------------------------------
// K1: independent pre-work. grid 544:
//   [0,32)    Wqk / Wqko fusion tiles (32x32 out each)
//   [32,288)  per (b, 16-row half): avA -> ws, delta -> LDS -> dproj -> ws
//   [288,544) per (b, m-half32): avO -> ws (no LDS)
// ---------------------------------------------------------------------------
__global__ __launch_bounds__(256, 4) void k1_pre(
    const float* __restrict__ g_states, const float* __restrict__ g_pol,
    const float* __restrict__ g_act, const float* __restrict__ g_so,
    const float* __restrict__ g_ao,
    const float* __restrict__ Wq, const float* __restrict__ Wk,
    const float* __restrict__ Wqo, const float* __restrict__ Wko,
    const float* __restrict__ W_av, const float* __restrict__ W_avo,
    const float* __restrict__ W_f1, float* __restrict__ ws)
{
  __shared__ __align__(16) float pool[8448];   // 33 KB
  const int t = threadIdx.x;
  int blk = blockIdx.x;

  if (blk < 32) {
    // ---- weight fusion: Wqk[c][e] = sum_d Wq[c,d]*Wk[e,d] ----------------
    const float* A; const float* Bm; float* O;
    if (blk < 16) { A = Wq;  Bm = Wk;  O = ws + WS_WQK; }
    else          { A = Wqo; Bm = Wko; O = ws + WS_WQKO; blk -= 16; }
    const int tr = (blk >> 2) << 5;
    const int tc = (blk & 3) << 5;
    float* sA = pool;                 // [32][132]
    float* sB = pool + 4224;          // [32][132]
    const float4* a4 = (const float4*)(A + tr * 128);
    const float4* b4 = (const float4*)(Bm + tc * 128);
    #pragma unroll
    for (int u = 0; u < 4; ++u) {
      int f = t + u * 256;
      int r = f >> 5, c4 = f & 31;
      *(float4*)(sA + r*132 + c4*4) = a4[f];
      *(float4*)(sB + r*132 + c4*4) = b4[f];
    }
    __syncthreads();
    const int e = t & 31, cl0 = t >> 5;
    float acc[4] = {0,0,0,0};
    #pragma unroll 4
    for (int d4 = 0; d4 < 32; ++d4) {
      float4 bv = *(const float4*)(sB + e*132 + d4*4);
      #pragma unroll
      for (int rr = 0; rr < 4; ++rr) {
        float4 av = *(const float4*)(sA + (cl0 + rr*8)*132 + d4*4);
        acc[rr] += dot4(av, bv);
      }
    }
    #pragma unroll
    for (int rr = 0; rr < 4; ++rr)
      O[(tr + cl0 + rr*8)*128 + tc + e] = acc[rr];
    return;
  }
  blk -= 32;

  if (blk < 256) {
    // ---- per (b, 16-row half): avA + delta + dproj -----------------------
    const int b = blk >> 1, k0 = (blk & 1) << 4;
    float* s_pre = pool;          // [16][132]: pre-act A at +0, P at +64
    float* s_dl  = pool + 2112;   // delta [16][68]
    const int rg = t >> 6, lane = t & 63;
    const int ap = rg & 1, sub = (rg >> 1) << 3;   // 8-row group
    {
      const float* gs = g_states + b*4096 + (k0 + sub)*128;
      const float* gt = (ap ? g_pol : g_act) + b*512 + (k0 + sub)*16;
      float acc[8] = {0,0,0,0,0,0,0,0};
      #pragma unroll 4
      for (int c4 = 0; c4 < 32; ++c4) {
        const float w0 = W_av[(c4*4+0)*64 + lane];
        const float w1 = W_av[(c4*4+1)*64 + lane];
        const float w2 = W_av[(c4*4+2)*64 + lane];
        const float w3 = W_av[(c4*4+3)*64 + lane];
        #pragma unroll
        for (int r = 0; r < 8; ++r) {
          float4 sv = *(const float4*)(gs + r*128 + c4*4);   // uniform
          acc[r] += sv.x*w0 + sv.y*w1 + sv.z*w2 + sv.w*w3;
        }
      }
      #pragma unroll
      for (int c4 = 0; c4 < 4; ++c4) {
        const float w0 = W_av[(128 + c4*4+0)*64 + lane];
        const float w1 = W_av[(128 + c4*4+1)*64 + lane];
        const float w2 = W_av[(128 + c4*4+2)*64 + lane];
        const float w3 = W_av[(128 + c4*4+3)*64 + lane];
        #pragma unroll
        for (int r = 0; r < 8; ++r) {
          float4 sv = *(const float4*)(gt + r*16 + c4*4);
          acc[r] += sv.x*w0 + sv.y*w1 + sv.z*w2 + sv.w*w3;
        }
      }
      #pragma unroll
      for (int r = 0; r < 8; ++r)
        s_pre[(sub + r)*132 + ap*64 + lane] = acc[r];
    }
    __syncthreads();
    {
      // combine: avA = tanh(preA) -> ws ; delta = tanh(preP) - avA -> LDS
      const int r = t >> 4, d0 = (t & 15) << 2;
      float4 a0 = *(const float4*)(s_pre + r*132 + d0);
      float4 p0 = *(const float4*)(s_pre + r*132 + 64 + d0);
      float4 va, dl;
      va.x = tanhf(a0.x); va.y = tanhf(a0.y); va.z = tanhf(a0.z); va.w = tanhf(a0.w);
      dl.x = tanhf(p0.x) - va.x; dl.y = tanhf(p0.y) - va.y;
      dl.z = tanhf(p0.z) - va.z; dl.w = tanhf(p0.w) - va.w;
      *(float4*)(ws + WS_AVA + b*2048 + (k0 + r)*64 + d0) = va;
      *(float4*)(s_dl + r*68 + d0) = dl;
    }
    __syncthreads();
    {
      // dproj[j][h] = sum_d delta[j][d] * W_f1a[d][h]; wave rg: 4 rows
      const int q0 = rg << 2;
      float acc[4] = {0,0,0,0};
      #pragma unroll 4
      for (int d4 = 0; d4 < 16; ++d4) {
        const float w0 = W_f1[(d4*4+0)*64 + lane];
        const float w1 = W_f1[(d4*4+1)*64 + lane];
        const float w2 = W_f1[(d4*4+2)*64 + lane];
        const float w3 = W_f1[(d4*4+3)*64 + lane];
        #pragma unroll
        for (int q = 0; q < 4; ++q) {
          float4 dv = *(const float4*)(s_dl + (q0+q)*68 + d4*4);  // uniform
          acc[q] += dv.x*w0 + dv.y*w1 + dv.z*w2 + dv.w*w3;
        }
      }
      #pragma unroll
      for (int q = 0; q < 4; ++q)
        ws[WS_DPROJ + b*2048 + (k0 + q0 + q)*64 + lane] = acc[q];
    }
    return;
  }
  blk -= 256;

  // ---- per (b, m-half32): avO -> ws (no LDS) -----------------------------
  {
    const int b = blk >> 1, m0 = (blk & 1) << 5;
    const int rg = t >> 6, lane = t & 63;
    const float* gso = g_so + (b*64 + m0 + rg*8) * 128;
    const float* gao = g_ao + (b*64 + m0 + rg*8) * 16;
    float acc[8] = {0,0,0,0,0,0,0,0};
    #pragma unroll 4
    for (int c4 = 0; c4 < 32; ++c4) {
      const float w0 = W_avo[(c4*4+0)*64 + lane];
      const float w1 = W_avo[(c4*4+1)*64 + lane];
      const float w2 = W_avo[(c4*4+2)*64 + lane];
      const float w3 = W_avo[(c4*4+3)*64 + lane];
      #pragma unroll
      for (int r = 0; r < 8; ++r) {
        float4 sv = *(const float4*)(gso + r*128 + c4*4);    // uniform
        acc[r] += sv.x*w0 + sv.y*w1 + sv.z*w2 + sv.w*w3;
      }
    }
    #pragma unroll
    for (int c4 = 0; c4 < 4; ++c4) {
      const float w0 = W_avo[(128 + c4*4+0)*64 + lane];
      const float w1 = W_avo[(128 + c4*4+1)*64 + lane];
      const float w2 = W_avo[(128 + c4*4+2)*64 + lane];
      const float w3 = W_avo[(128 + c4*4+3)*64 + lane];
      #pragma unroll
      for (int r = 0; r < 8; ++r) {
        float4 sv = *(const float4*)(gao + r*16 + c4*4);
        acc[r] += sv.x*w0 + sv.y*w1 + sv.z*w2 + sv.w*w3;
      }
    }
    #pragma unroll
    for (int r = 0; r < 8; ++r)
      ws[WS_AVO + b*4096 + (m0 + rg*8 + r)*64 + lane] = tanhf(acc[r]);
  }
}

// ---------------------------------------------------------------------------
// K2: main, per (b, i-octile). grid 512. LDS 13376 floats = 52.25 KB (3/CU).
//   s_avA [32][68] @0, s_avO [64][68] @2176, s_dp [32][68] @6528,
//   s_P [8][268] @8704, s_w [8][36] @10848, s_wo [8][68] @11136,
//   s_S [8][68] @11680, s_wavo [8][68] @12224, s_base [8][68] @12768,
//   s_wf2 [64] @13312
// ---------------------------------------------------------------------------
__global__ __launch_bounds__(256, 4) void k2_main(
    const float* __restrict__ g_states, const float* __restrict__ g_so,
    const float* __restrict__ W_f1, const float* __restrict__ W_f2,
    const float* __restrict__ ws, float* __restrict__ out)
{
  __shared__ __align__(16) float pool[13376];
  float* s_avA  = pool;
  float* s_avO  = pool + 2176;
  float* s_dp   = pool + 6528;
  float* s_P    = pool + 8704;
  float* s_w    = pool + 10848;
  float* s_wo   = pool + 11136;
  float* s_S    = pool + 11680;
  float* s_wavo = pool + 12224;
  float* s_base = pool + 12768;
  float* s_wf2  = pool + 13312;

  const int t = threadIdx.x;
  const int b = blockIdx.x >> 2;
  const int i0 = (blockIdx.x & 3) << 3;

  // ---- ph1: stage avA, avO, dproj, wf2 (used from ph7 on) ----------------
  #pragma unroll
  for (int u = 0; u < 2; ++u) {
    int f = t + u * 256;                  // 0..511 float4
    int k = f >> 4, dq = f & 15;
    *(float4*)(s_avA + k*68 + dq*4) = ((const float4*)(ws + WS_AVA + b*2048))[f];
    *(float4*)(s_dp  + k*68 + dq*4) = ((const float4*)(ws + WS_DPROJ + b*2048))[f];
  }
  #pragma unroll
  for (int u = 0; u < 4; ++u) {
    int f = t + u * 256;
    int m = f >> 4, dq = f & 15;
    *(float4*)(s_avO + m*68 + dq*4) = ((const float4*)(ws + WS_AVO + b*4096))[f];
  }
  if (t < 16) *(float4*)(s_wf2 + t*4) = ((const float4*)W_f2)[t];

  // ---- ph2: P = states[i0..+8] @ [Wqk|Wqko], register-resident -----------
  {
    const int wv = t >> 6, lane = t & 63;
    const int cg = wv*64 + lane;                 // col 0..255
    const float* Wp = (wv < 2) ? (ws + WS_WQK  + cg)
                               : (ws + WS_WQKO + cg - 128);
    const float* srow = g_states + b*4096 + i0*128;
    float acc[8] = {0,0,0,0,0,0,0,0};
    #pragma unroll 4
    for (int c4 = 0; c4 < 32; ++c4) {
      float4 sv[8];
      #pragma unroll
      for (int r = 0; r < 8; ++r)
        sv[r] = *(const float4*)(srow + r*128 + c4*4);   // uniform
      #pragma unroll
      for (int kk = 0; kk < 4; ++kk) {
        float wvv = Wp[(c4*4 + kk)*128];                 // coalesced
        #pragma unroll
        for (int r = 0; r < 8; ++r)
          acc[r] += wvv * ((const float*)&sv[r])[kk];
      }
    }
    #pragma unroll
    for (int r = 0; r < 8; ++r)
      s_P[r*268 + cg] = acc[r];
  }
  __syncthreads();

  // ---- ph3: self scores + softmax; then other scores (no extra barrier) --
  {
    const int r = t >> 5, j = t & 31;
    float acc = 0.f;
    #pragma unroll 8
    for (int e4 = 0; e4 < 32; ++e4) {
      float4 p4  = *(const float4*)(s_P + r*268 + e4*4);
      float4 st4 = *(const float4*)(g_states + b*4096 + j*128 + e4*4); // gather
      acc += dot4(p4, st4);
    }
    acc *= INV_SQRT_DK;
    float mx = acc;
    for (int off = 16; off; off >>= 1) mx = fmaxf(mx, __shfl_xor(mx, off, 32));
    float ev = __expf(acc - mx);
    float sum = ev;
    for (int off = 16; off; off >>= 1) sum += __shfl_xor(sum, off, 32);
    float wn = ev / sum;
    out[131072 + b*1024 + (i0 + r)*32 + j] = wn;
    s_w[r*36 + j] = wn;

    #pragma unroll
    for (int tt = 0; tt < 2; ++tt) {
      float a2 = 0.f;
      #pragma unroll 8
      for (int c4 = 0; c4 < 32; ++c4) {
        float4 p4  = *(const float4*)(s_P + r*268 + 128 + c4*4);
        float4 so4 = *(const float4*)(g_so + (b*64 + tt*32 + j)*128 + c4*4);
        a2 += dot4(p4, so4);
      }
      s_wo[r*68 + tt*32 + j] = a2 * INV_SQRT_DK;
    }
  }
  __syncthreads();

  // ---- ph6: softmax wo + write weight_other ------------------------------
  #pragma unroll
  for (int p = 0; p < 2; ++p) {
    const int r = (t >> 6) + (p << 2), l = t & 63;
    float v = s_wo[r*68 + l];
    float mx = v;
    for (int off = 32; off; off >>= 1) mx = fmaxf(mx, __shfl_xor(mx, off, 64));
    float ev = __expf(v - mx);
    float sum = ev;
    for (int off = 32; off; off >>= 1) sum += __shfl_xor(sum, off, 64);
    float wn = ev / sum;
    out[262144 + b*2048 + (i0 + r)*64 + l] = wn;
    s_wo[r*68 + l] = wn;
  }
  __syncthreads();

  // ---- ph7: S = w @ avA (t<128); wavo = wo @ avO (t>=128) ----------------
  if (t < 128) {
    const int i = t >> 4, dq = (t & 15) << 2;
    float4 acc = {0,0,0,0};
    #pragma unroll 4
    for (int k = 0; k < 32; ++k) {
      float4 a4 = *(const float4*)(s_avA + k*68 + dq);
      float wv = s_w[i*36 + k];
      acc.x += wv*a4.x; acc.y += wv*a4.y; acc.z += wv*a4.z; acc.w += wv*a4.w;
    }
    *(float4*)(s_S + i*68 + dq) = acc;
  } else {
    const int tt2 = t - 128;
    const int i = tt2 >> 4, dq = (tt2 & 15) << 2;
    float4 acc = {0,0,0,0};
    #pragma unroll 4
    for (int m = 0; m < 64; ++m) {
      float4 a4 = *(const float4*)(s_avO + m*68 + dq);
      float wv = s_wo[i*68 + m];
      acc.x += wv*a4.x; acc.y += wv*a4.y; acc.z += wv*a4.z; acc.w += wv*a4.w;
    }
    *(float4*)(s_wavo + i*68 + dq) = acc;
  }
  __syncthreads();

  // ---- ph8: base = S@Wf1a + wavo@Wf1b ------------------------------------
  {
    const int h = t & 63, g = (t >> 6) << 1;
    float a0 = 0.f, a1 = 0.f;
    #pragma unroll 4
    for (int d = 0; d < 64; ++d) {
      float w1v = W_f1[d*64 + h];
      float w2v = W_f1[(64 + d)*64 + h];
      a0 += s_S[g*68 + d]*w1v + s_wavo[g*68 + d]*w2v;
      a1 += s_S[(g+1)*68 + d]*w1v + s_wavo[(g+1)*68 + d]*w2v;
    }
    s_base[g*68 + h] = a0;
    s_base[(g+1)*68 + h] = a1;
  }
  __syncthreads();

  // ---- ph9: value[i][j] = sum_h lrelu(base[i,h]+w[i,j]*dproj[j,h])*Wf2[h] -
  {
    const int i = t >> 5, j = t & 31;
    const float wij = s_w[i*36 + j];
    float acc = 0.f;
    #pragma unroll 4
    for (int hq = 0; hq < 16; ++hq) {
      float4 b4 = *(const float4*)(s_base + i*68 + hq*4);
      float4 d4 = *(const float4*)(s_dp + j*68 + hq*4);
      float4 f4 = *(const float4*)(s_wf2 + hq*4);
      float p0 = b4.x + wij*d4.x; p0 = p0 > 0.f ? p0 : 0.01f*p0;
      float p1 = b4.y + wij*d4.y; p1 = p1 > 0.f ? p1 : 0.01f*p1;
      float p2 = b4.z + wij*d4.z; p2 = p2 > 0.f ? p2 : 0.01f*p2;
      float p3 = b4.w + wij*d4.w; p3 = p3 > 0.f ? p3 : 0.01f*p3;
      acc += p0*f4.x + p1*f4.y + p2*f4.z + p3*f4.w;
    }
    out[b*1024 + (i0 + i)*32 + j] = acc;
  }
}

extern "C" void kernel_launch(void* const* d_in, const int* in_sizes, int n_in,
                              void* d_out, int out_size, void* d_ws, size_t ws_size,
                              hipStream_t stream) {
  const float* states        = (const float*)d_in[0];
  const float* policies      = (const float*)d_in[1];
  const float* actions       = (const float*)d_in[2];
  const float* states_other  = (const float*)d_in[3];
  const float* actions_other = (const float*)d_in[4];
  const float* W_key         = (const float*)d_in[5];
  const float* W_query       = (const float*)d_in[6];
  const float* W_av          = (const float*)d_in[7];
  const float* W_key_other   = (const float*)d_in[8];
  const float* W_query_other = (const float*)d_in[9];
  const float* W_av_other    = (const float*)d_in[10];
  const float* W_f1          = (const float*)d_in[11];
  const float* W_f2          = (const float*)d_in[12];
  float* out = (float*)d_out;
  float* ws  = (float*)d_ws;   // 4.125 MB used

  k1_pre<<<544, 256, 0, stream>>>(states, policies, actions, states_other,
                                  actions_other, W_query, W_key,
                                  W_query_other, W_key_other, W_av, W_av_other,
                                  W_f1, ws);
  k2_main<<<512, 256, 0, stream>>>(states, states_other, W_f1, W_f2, ws, out);
}

// Round 8
// 132.305 us; speedup vs baseline: 1.4419x; 1.2819x over previous
//
#include <hip/hip_runtime.h>
#include <math.h>

// Problem constants (fixed by reference)
//  B=128, N=32, M=64, OBS=128, ACT=16, D_QK=128, D_AV=64, F_IN=144, H=64
// Outputs concatenated: value [B,32,32] @0, ret_weight [B,32,32] @131072,
// weight_other [B,32,64] @262144.
//
// Workspace (floats), 1,081,344 floats = 4.125 MB:
#define WS_WQK   0         // [128][128]
#define WS_WQKO  16384     // [128][128]
#define WS_AVA   32768     // [B][32][64]
#define WS_AVO   294912    // [B][64][64]
#define WS_DPROJ 819200    // [B][32][64]

#define INV_SQRT_DK 0.08838834764831845f  // 1/sqrt(128)

__device__ __forceinline__ float dot4(float4 a, float4 b) {
  return a.x*b.x + a.y*b.y + a.z*b.z + a.w*b.w;
}
__device__ __forceinline__ void fma4(float4& a, const float4 w, const float s) {
  a.x += w.x*s; a.y += w.y*s; a.z += w.z*s; a.w += w.w*s;
}

// ---------------------------------------------------------------------------
// K1: independent pre-work (exact R4 structure, VGPR unclamped). grid 416:
//   [0,32)    Wqk / Wqko fusion tiles (32x32 out each)
//   [32,160)  avA + delta + dproj per b   (wave-uniform input reads)
//   [160,416) avO per (b, m-half)         (no LDS)
// ---------------------------------------------------------------------------
__global__ __launch_bounds__(256) void k1_pre(
    const float* __restrict__ g_states, const float* __restrict__ g_pol,
    const float* __restrict__ g_act, const float* __restrict__ g_so,
    const float* __restrict__ g_ao,
    const float* __restrict__ Wq, const float* __restrict__ Wk,
    const float* __restrict__ Wqo, const float* __restrict__ Wko,
    const float* __restrict__ W_av, const float* __restrict__ W_avo,
    const float* __restrict__ W_f1, float* __restrict__ ws)
{
  __shared__ __align__(16) float pool[8448];   // 33 KB
  const int t = threadIdx.x;
  int blk = blockIdx.x;

  if (blk < 32) {
    // ---- weight fusion: Wqk[c][e] = sum_d Wq[c,d]*Wk[e,d] ----------------
    const float* A; const float* Bm; float* O;
    if (blk < 16) { A = Wq;  Bm = Wk;  O = ws + WS_WQK; }
    else          { A = Wqo; Bm = Wko; O = ws + WS_WQKO; blk -= 16; }
    const int tr = (blk >> 2) << 5;
    const int tc = (blk & 3) << 5;
    float* sA = pool;                 // [32][132]
    float* sB = pool + 4224;          // [32][132]
    const float4* a4 = (const float4*)(A + tr * 128);
    const float4* b4 = (const float4*)(Bm + tc * 128);
    #pragma unroll
    for (int u = 0; u < 4; ++u) {
      int f = t + u * 256;
      int r = f >> 5, c4 = f & 31;
      *(float4*)(sA + r*132 + c4*4) = a4[f];
      *(float4*)(sB + r*132 + c4*4) = b4[f];
    }
    __syncthreads();
    const int e = t & 31, cl0 = t >> 5;
    float acc[4] = {0,0,0,0};
    #pragma unroll 4
    for (int d4 = 0; d4 < 32; ++d4) {
      float4 bv = *(const float4*)(sB + e*132 + d4*4);
      #pragma unroll
      for (int rr = 0; rr < 4; ++rr) {
        float4 av = *(const float4*)(sA + (cl0 + rr*8)*132 + d4*4);
        acc[rr] += dot4(av, bv);
      }
    }
    #pragma unroll
    for (int rr = 0; rr < 4; ++rr)
      O[(tr + cl0 + rr*8)*128 + tc + e] = acc[rr];
    return;
  }
  blk -= 32;

  if (blk < 128) {
    // ---- per b: pre-acts -> avA (ws), delta (LDS) -> dproj (ws) ----------
    const int b = blk;
    float* s_pre = pool;          // [32][132]: pre-act A at +0, P at +64
    float* s_dl  = pool + 4224;   // delta [32][68]
    {
      const int wv_  = t >> 6;          // wave 0..3
      const int ap   = wv_ & 1;         // 0 = actions, 1 = policies
      const int rh   = wv_ >> 1;        // row half (16 rows)
      const int lane = t & 63;          // d column
      const float* gs = g_states + b*4096 + rh*16*128;
      const float* gt = (ap ? g_pol : g_act) + b*512 + rh*16*16;
      float acc[16];
      #pragma unroll
      for (int r = 0; r < 16; ++r) acc[r] = 0.f;
      #pragma unroll 4
      for (int c4 = 0; c4 < 32; ++c4) {          // shared c < 128
        const float w0 = W_av[(c4*4+0)*64 + lane];
        const float w1 = W_av[(c4*4+1)*64 + lane];
        const float w2 = W_av[(c4*4+2)*64 + lane];
        const float w3 = W_av[(c4*4+3)*64 + lane];
        #pragma unroll
        for (int r = 0; r < 16; ++r) {
          float4 sv = *(const float4*)(gs + r*128 + c4*4);  // uniform
          acc[r] += sv.x*w0 + sv.y*w1 + sv.z*w2 + sv.w*w3;
        }
      }
      #pragma unroll
      for (int c4 = 0; c4 < 4; ++c4) {           // tail c in [128,144)
        const float w0 = W_av[(128 + c4*4+0)*64 + lane];
        const float w1 = W_av[(128 + c4*4+1)*64 + lane];
        const float w2 = W_av[(128 + c4*4+2)*64 + lane];
        const float w3 = W_av[(128 + c4*4+3)*64 + lane];
        #pragma unroll
        for (int r = 0; r < 16; ++r) {
          float4 sv = *(const float4*)(gt + r*16 + c4*4);
          acc[r] += sv.x*w0 + sv.y*w1 + sv.z*w2 + sv.w*w3;
        }
      }
      #pragma unroll
      for (int r = 0; r < 16; ++r)
        s_pre[(rh*16 + r)*132 + ap*64 + lane] = acc[r];
    }
    __syncthreads();
    {
      // combine: avA = tanh(preA) -> ws ; delta = tanh(preP) - avA -> LDS
      const int r = t >> 3, d0 = (t & 7) << 3;
      float4 a0 = *(const float4*)(s_pre + r*132 + d0);
      float4 a1 = *(const float4*)(s_pre + r*132 + d0 + 4);
      float4 p0 = *(const float4*)(s_pre + r*132 + 64 + d0);
      float4 p1 = *(const float4*)(s_pre + r*132 + 64 + d0 + 4);
      float4 va0, va1, dl0, dl1;
      va0.x = tanhf(a0.x); va0.y = tanhf(a0.y); va0.z = tanhf(a0.z); va0.w = tanhf(a0.w);
      va1.x = tanhf(a1.x); va1.y = tanhf(a1.y); va1.z = tanhf(a1.z); va1.w = tanhf(a1.w);
      dl0.x = tanhf(p0.x) - va0.x; dl0.y = tanhf(p0.y) - va0.y;
      dl0.z = tanhf(p0.z) - va0.z; dl0.w = tanhf(p0.w) - va0.w;
      dl1.x = tanhf(p1.x) - va1.x; dl1.y = tanhf(p1.y) - va1.y;
      dl1.z = tanhf(p1.z) - va1.z; dl1.w = tanhf(p1.w) - va1.w;
      *(float4*)(ws + WS_AVA + b*2048 + r*64 + d0)     = va0;
      *(float4*)(ws + WS_AVA + b*2048 + r*64 + d0 + 4) = va1;
      *(float4*)(s_dl + r*68 + d0)     = dl0;
      *(float4*)(s_dl + r*68 + d0 + 4) = dl1;
    }
    __syncthreads();
    {
      // dproj[j][h] = sum_d delta[j][d] * W_f1a[d][h]
      const int h = t & 63;
      const int j0 = (t >> 6) << 3;     // 8 rows per wave
      float acc[8] = {0,0,0,0,0,0,0,0};
      #pragma unroll 4
      for (int d4 = 0; d4 < 16; ++d4) {
        float w0 = W_f1[(d4*4+0)*64 + h];
        float w1 = W_f1[(d4*4+1)*64 + h];
        float w2 = W_f1[(d4*4+2)*64 + h];
        float w3 = W_f1[(d4*4+3)*64 + h];
        #pragma unroll
        for (int q = 0; q < 8; ++q) {
          float4 dv = *(const float4*)(s_dl + (j0+q)*68 + d4*4);  // uniform
          acc[q] += dv.x*w0 + dv.y*w1 + dv.z*w2 + dv.w*w3;
        }
      }
      #pragma unroll
      for (int q = 0; q < 8; ++q)
        ws[WS_DPROJ + b*2048 + (j0+q)*64 + h] = acc[q];
    }
    return;
  }
  blk -= 128;

  // ---- avO per (b, 32-row half): wave = 8-row group, lane = d ------------
  {
    const int b = blk >> 1, m0 = (blk & 1) << 5;
    const int rg = t >> 6, lane = t & 63;
    const float* gso = g_so + (b*64 + m0 + rg*8) * 128;
    const float* gao = g_ao + (b*64 + m0 + rg*8) * 16;
    float acc[8] = {0,0,0,0,0,0,0,0};
    #pragma unroll 4
    for (int c4 = 0; c4 < 32; ++c4) {
      const float w0 = W_avo[(c4*4+0)*64 + lane];
      const float w1 = W_avo[(c4*4+1)*64 + lane];
      const float w2 = W_avo[(c4*4+2)*64 + lane];
      const float w3 = W_avo[(c4*4+3)*64 + lane];
      #pragma unroll
      for (int r = 0; r < 8; ++r) {
        float4 sv = *(const float4*)(gso + r*128 + c4*4);    // uniform
        acc[r] += sv.x*w0 + sv.y*w1 + sv.z*w2 + sv.w*w3;
      }
    }
    #pragma unroll
    for (int c4 = 0; c4 < 4; ++c4) {
      const float w0 = W_avo[(128 + c4*4+0)*64 + lane];
      const float w1 = W_avo[(128 + c4*4+1)*64 + lane];
      const float w2 = W_avo[(128 + c4*4+2)*64 + lane];
      const float w3 = W_avo[(128 + c4*4+3)*64 + lane];
      #pragma unroll
      for (int r = 0; r < 8; ++r) {
        float4 sv = *(const float4*)(gao + r*16 + c4*4);
        acc[r] += sv.x*w0 + sv.y*w1 + sv.z*w2 + sv.w*w3;
      }
    }
    #pragma unroll
    for (int r = 0; r < 8; ++r)
      ws[WS_AVO + b*4096 + (m0 + rg*8 + r)*64 + lane] = tanhf(acc[r]);
  }
}

// ---------------------------------------------------------------------------
// K2: main, per (b, i-octile). grid 512. LDS 13376 floats = 52.25 KB (3/CU).
//   A      @0     [4352]: states [32][132] / so tiles [32][132] / avO [64][68]
//   avA    @4352  [2176]: [32][68]
//   dp     @6528  [2176]: [32][68]
//   P      @8704  [2144]: [8][268]  (P1 cols 0..127, P2 cols 128..255)
//   w      @10848 [288] : [8][36]
//   wo     @11136 [544] : [8][68]
//   S      @11680 [544] : [8][68]
//   wavo   @12224 [544]
//   base   @12768 [544]
//   wf2    @13312 [64]
// ---------------------------------------------------------------------------
__global__ __launch_bounds__(256) void k2_main(
    const float* __restrict__ g_states, const float* __restrict__ g_so,
    const float* __restrict__ W_f1, const float* __restrict__ W_f2,
    const float* __restrict__ ws, float* __restrict__ out)
{
  __shared__ __align__(16) float pool[13376];
  float* s_st   = pool;
  float* s_avO  = pool;            // alias A (after so tiles done)
  float* s_avA  = pool + 4352;
  float* s_dp   = pool + 6528;
  float* s_P    = pool + 8704;
  float* s_w    = pool + 10848;
  float* s_wo   = pool + 11136;
  float* s_S    = pool + 11680;
  float* s_wavo = pool + 12224;
  float* s_base = pool + 12768;
  float* s_wf2  = pool + 13312;

  const int t = threadIdx.x;
  const int b = blockIdx.x >> 2;
  const int i0 = (blockIdx.x & 3) << 3;

  // ---- ph1: stage states (for ph3 j-side), avA, dproj, wf2 ---------------
  {
    const float4* gs4 = (const float4*)(g_states + b * 4096);
    #pragma unroll
    for (int u = 0; u < 4; ++u) {
      int f = t + u * 256;
      int r = f >> 5, c4 = f & 31;
      *(float4*)(s_st + r*132 + c4*4) = gs4[f];
    }
    #pragma unroll
    for (int u = 0; u < 2; ++u) {
      int f = t + u * 256;                  // 0..511 float4
      int k = f >> 4, dq = f & 15;
      *(float4*)(s_avA + k*68 + dq*4) = ((const float4*)(ws + WS_AVA + b*2048))[f];
      *(float4*)(s_dp  + k*68 + dq*4) = ((const float4*)(ws + WS_DPROJ + b*2048))[f];
    }
    if (t < 16) *(float4*)(s_wf2 + t*4) = ((const float4*)W_f2)[t];
  }

  // ---- ph2: P = states[i0..+8] @ [Wqk|Wqko], register-resident row-split -
  // wave owns 2 output rows; lane owns f4-col (4 floats) of [P1|P2];
  // W read coalesced b128; states rows via wave-uniform loads.
  {
    const int wv = t >> 6, lane = t & 63;
    const int r0 = wv * 2;
    const float* Wbase = (lane < 32) ? (ws + WS_WQK  + lane*4)
                                     : (ws + WS_WQKO + (lane-32)*4);
    const float* srow0 = g_states + b*4096 + (i0 + r0)*128;
    const float* srow1 = srow0 + 128;
    float4 a0 = {0,0,0,0}, a1 = {0,0,0,0};
    #pragma unroll 4
    for (int c4 = 0; c4 < 32; ++c4) {
      float4 s0 = *(const float4*)(srow0 + c4*4);   // uniform
      float4 s1 = *(const float4*)(srow1 + c4*4);
      #pragma unroll
      for (int kk = 0; kk < 4; ++kk) {
        float4 wv4 = *(const float4*)(Wbase + (c4*4 + kk)*128);  // coalesced
        fma4(a0, wv4, ((const float*)&s0)[kk]);
        fma4(a1, wv4, ((const float*)&s1)[kk]);
      }
    }
    *(float4*)(s_P + r0*268 + lane*4)       = a0;
    *(float4*)(s_P + (r0+1)*268 + lane*4)   = a1;
  }
  __syncthreads();

  // ---- ph3: self scores + register softmax + write ret_weight ------------
  {
    const int r = t >> 5, j = t & 31;
    float acc = 0.f;
    #pragma unroll 8
    for (int e4 = 0; e4 < 32; ++e4) {
      float4 p4  = *(const float4*)(s_P + r*268 + e4*4);
      float4 st4 = *(const float4*)(s_st + j*132 + e4*4);
      acc += dot4(p4, st4);
    }
    acc *= INV_SQRT_DK;
    float mx = acc;
    for (int off = 16; off; off >>= 1) mx = fmaxf(mx, __shfl_xor(mx, off, 32));
    float ev = __expf(acc - mx);
    float sum = ev;
    for (int off = 16; off; off >>= 1) sum += __shfl_xor(sum, off, 32);
    float wn = ev / sum;
    out[131072 + b*1024 + (i0 + r)*32 + j] = wn;
    s_w[r*36 + j] = wn;
  }
  __syncthreads();

  // ---- ph4/5: other scores over two states_other tiles -------------------
  for (int tt = 0; tt < 2; ++tt) {
    const float4* gt4 = (const float4*)(g_so + (b*64 + tt*32) * 128);
    #pragma unroll
    for (int u = 0; u < 4; ++u) {
      int f = t + u * 256;
      int r = f >> 5, c4 = f & 31;
      *(float4*)(s_st + r*132 + c4*4) = gt4[f];
    }
    __syncthreads();
    const int r = t >> 5, m = t & 31;
    float acc = 0.f;
    #pragma unroll 8
    for (int c4 = 0; c4 < 32; ++c4) {
      float4 p4  = *(const float4*)(s_P + r*268 + 128 + c4*4);
      float4 st4 = *(const float4*)(s_st + m*132 + c4*4);
      acc += dot4(p4, st4);
    }
    s_wo[r*68 + tt*32 + m] = acc * INV_SQRT_DK;
    __syncthreads();
  }

  // ---- ph6: softmax wo + write weight_other; stage avO -------------------
  #pragma unroll
  for (int p = 0; p < 2; ++p) {
    const int r = (t >> 6) + (p << 2), l = t & 63;
    float v = s_wo[r*68 + l];
    float mx = v;
    for (int off = 32; off; off >>= 1) mx = fmaxf(mx, __shfl_xor(mx, off, 64));
    float ev = __expf(v - mx);
    float sum = ev;
    for (int off = 32; off; off >>= 1) sum += __shfl_xor(sum, off, 64);
    float wn = ev / sum;
    out[262144 + b*2048 + (i0 + r)*64 + l] = wn;
    s_wo[r*68 + l] = wn;
  }
  #pragma unroll
  for (int u = 0; u < 4; ++u) {
    int f = t + u * 256;
    int m = f >> 4, dq = f & 15;
    *(float4*)(s_avO + m*68 + dq*4) = ((const float4*)(ws + WS_AVO + b*4096))[f];
  }
  __syncthreads();

  // ---- ph7: S = w @ avA (t<128); wavo = wo @ avO (t>=128) ----------------
  if (t < 128) {
    const int i = t >> 4, dq = (t & 15) << 2;
    float4 acc = {0,0,0,0};
    #pragma unroll 4
    for (int k = 0; k < 32; ++k) {
      float4 a4 = *(const float4*)(s_avA + k*68 + dq);
      float wv = s_w[i*36 + k];
      acc.x += wv*a4.x; acc.y += wv*a4.y; acc.z += wv*a4.z; acc.w += wv*a4.w;
    }
    *(float4*)(s_S + i*68 + dq) = acc;
  } else {
    const int tt2 = t - 128;
    const int i = tt2 >> 4, dq = (tt2 & 15) << 2;
    float4 acc = {0,0,0,0};
    #pragma unroll 4
    for (int m = 0; m < 64; ++m) {
      float4 a4 = *(const float4*)(s_avO + m*68 + dq);
      float wv = s_wo[i*68 + m];
      acc.x += wv*a4.x; acc.y += wv*a4.y; acc.z += wv*a4.z; acc.w += wv*a4.w;
    }
    *(float4*)(s_wavo + i*68 + dq) = acc;
  }
  __syncthreads();

  // ---- ph8: base = S@Wf1a + wavo@Wf1b ------------------------------------
  {
    const int h = t & 63, g = (t >> 6) << 1;
    float a0 = 0.f, a1 = 0.f;
    #pragma unroll 4
    for (int d = 0; d < 64; ++d) {
      float w1v = W_f1[d*64 + h];
      float w2v = W_f1[(64 + d)*64 + h];
      a0 += s_S[g*68 + d]*w1v + s_wavo[g*68 + d]*w2v;
      a1 += s_S[(g+1)*68 + d]*w1v + s_wavo[(g+1)*68 + d]*w2v;
    }
    s_base[g*68 + h] = a0;
    s_base[(g+1)*68 + h] = a1;
  }
  __syncthreads();

  // ---- ph9: value[i][j] = sum_h lrelu(base[i,h]+w[i,j]*dproj[j,h])*Wf2[h] -
  {
    const int i = t >> 5, j = t & 31;
    const float wij = s_w[i*36 + j];
    float acc = 0.f;
    #pragma unroll 4
    for (int hq = 0; hq < 16; ++hq) {
      float4 b4 = *(const float4*)(s_base + i*68 + hq*4);
      float4 d4 = *(const float4*)(s_dp + j*68 + hq*4);
      float4 f4 = *(const float4*)(s_wf2 + hq*4);
      float p0 = b4.x + wij*d4.x; p0 = p0 > 0.f ? p0 : 0.01f*p0;
      float p1 = b4.y + wij*d4.y; p1 = p1 > 0.f ? p1 : 0.01f*p1;
      float p2 = b4.z + wij*d4.z; p2 = p2 > 0.f ? p2 : 0.01f*p2;
      float p3 = b4.w + wij*d4.w; p3 = p3 > 0.f ? p3 : 0.01f*p3;
      acc += p0*f4.x + p1*f4.y + p2*f4.z + p3*f4.w;
    }
    out[b*1024 + (i0 + i)*32 + j] = acc;
  }
}

extern "C" void kernel_launch(void* const* d_in, const int* in_sizes, int n_in,
                              void* d_out, int out_size, void* d_ws, size_t ws_size,
                              hipStream_t stream) {
  const float* states        = (const float*)d_in[0];
  const float* policies      = (const float*)d_in[1];
  const float* actions       = (const float*)d_in[2];
  const float* states_other  = (const float*)d_in[3];
  const float* actions_other = (const float*)d_in[4];
  const float* W_key         = (const float*)d_in[5];
  const float* W_query       = (const float*)d_in[6];
  const float* W_av          = (const float*)d_in[7];
  const float* W_key_other   = (const float*)d_in[8];
  const float* W_query_other = (const float*)d_in[9];
  const float* W_av_other    = (const float*)d_in[10];
  const float* W_f1          = (const float*)d_in[11];
  const float* W_f2          = (const float*)d_in[12];
  float* out = (float*)d_out;
  float* ws  = (float*)d_ws;   // 4.125 MB used

  k1_pre<<<416, 256, 0, stream>>>(states, policies, actions, states_other,
                                  actions_other, W_query, W_key,
                                  W_query_other, W_key_other, W_av, W_av_other,
                                  W_f1, ws);
  k2_main<<<512, 256, 0, stream>>>(states, states_other, W_f1, W_f2, ws, out);
}

// Round 9
// 130.429 us; speedup vs baseline: 1.4626x; 1.0144x over previous
//
#include <hip/hip_runtime.h>
#include <math.h>

// Problem constants (fixed by reference)
//  B=128, N=32, M=64, OBS=128, ACT=16, D_QK=128, D_AV=64, F_IN=144, H=64
// Outputs concatenated: value [B,32,32] @0, ret_weight [B,32,32] @131072,
// weight_other [B,32,64] @262144.
//
// Workspace (floats), 1,081,344 floats = 4.125 MB:
#define WS_WQK   0         // [128][128]
#define WS_WQKO  16384     // [128][128]
#define WS_AVA   32768     // [B][32][64]
#define WS_AVO   294912    // [B][64][64]
#define WS_DPROJ 819200    // [B][32][64]

#define INV_SQRT_DK 0.08838834764831845f  // 1/sqrt(128)

__device__ __forceinline__ float dot4(float4 a, float4 b) {
  return a.x*b.x + a.y*b.y + a.z*b.z + a.w*b.w;
}
__device__ __forceinline__ void fma4(float4& a, const float4 w, const float s) {
  a.x += w.x*s; a.y += w.y*s; a.z += w.z*s; a.w += w.w*s;
}

// ---------------------------------------------------------------------------
// K1: independent pre-work, fine-grained. grid 800:
//   [0,32)    Wqk / Wqko fusion tiles (32x32 out each)
//   [32,288)  per (b, 16-row half): avA -> ws, delta -> LDS -> dproj -> ws
//   [288,800) per (b, 16-row quarter): avO -> ws (no LDS)
// No min-waves clamp (R7 lesson: VGPR=64 clamp causes scratch spills here).
// ---------------------------------------------------------------------------
__global__ __launch_bounds__(256) void k1_pre(
    const float* __restrict__ g_states, const float* __restrict__ g_pol,
    const float* __restrict__ g_act, const float* __restrict__ g_so,
    const float* __restrict__ g_ao,
    const float* __restrict__ Wq, const float* __restrict__ Wk,
    const float* __restrict__ Wqo, const float* __restrict__ Wko,
    const float* __restrict__ W_av, const float* __restrict__ W_avo,
    const float* __restrict__ W_f1, float* __restrict__ ws)
{
  __shared__ __align__(16) float pool[8448];   // 33 KB (fusion branch size)
  const int t = threadIdx.x;
  int blk = blockIdx.x;

  if (blk < 32) {
    // ---- weight fusion: Wqk[c][e] = sum_d Wq[c,d]*Wk[e,d] ----------------
    const float* A; const float* Bm; float* O;
    if (blk < 16) { A = Wq;  Bm = Wk;  O = ws + WS_WQK; }
    else          { A = Wqo; Bm = Wko; O = ws + WS_WQKO; blk -= 16; }
    const int tr = (blk >> 2) << 5;
    const int tc = (blk & 3) << 5;
    float* sA = pool;                 // [32][132]
    float* sB = pool + 4224;          // [32][132]
    const float4* a4 = (const float4*)(A + tr * 128);
    const float4* b4 = (const float4*)(Bm + tc * 128);
    #pragma unroll
    for (int u = 0; u < 4; ++u) {
      int f = t + u * 256;
      int r = f >> 5, c4 = f & 31;
      *(float4*)(sA + r*132 + c4*4) = a4[f];
      *(float4*)(sB + r*132 + c4*4) = b4[f];
    }
    __syncthreads();
    const int e = t & 31, cl0 = t >> 5;
    float acc[4] = {0,0,0,0};
    #pragma unroll 4
    for (int d4 = 0; d4 < 32; ++d4) {
      float4 bv = *(const float4*)(sB + e*132 + d4*4);
      #pragma unroll
      for (int rr = 0; rr < 4; ++rr) {
        float4 av = *(const float4*)(sA + (cl0 + rr*8)*132 + d4*4);
        acc[rr] += dot4(av, bv);
      }
    }
    #pragma unroll
    for (int rr = 0; rr < 4; ++rr)
      O[(tr + cl0 + rr*8)*128 + tc + e] = acc[rr];
    return;
  }
  blk -= 32;

  if (blk < 256) {
    // ---- per (b, 16-row half): avA + delta + dproj -----------------------
    const int b = blk >> 1, k0 = (blk & 1) << 4;
    float* s_pre = pool;          // [16][132]: pre-act A at +0, P at +64
    float* s_dl  = pool + 2112;   // delta [16][68]
    const int rg = t >> 6, lane = t & 63;
    const int ap = rg & 1, sub = (rg >> 1) << 3;   // 8-row group
    {
      const float* gs = g_states + b*4096 + (k0 + sub)*128;
      const float* gt = (ap ? g_pol : g_act) + b*512 + (k0 + sub)*16;
      float acc[8] = {0,0,0,0,0,0,0,0};
      #pragma unroll 4
      for (int c4 = 0; c4 < 32; ++c4) {          // shared c < 128
        const float w0 = W_av[(c4*4+0)*64 + lane];
        const float w1 = W_av[(c4*4+1)*64 + lane];
        const float w2 = W_av[(c4*4+2)*64 + lane];
        const float w3 = W_av[(c4*4+3)*64 + lane];
        #pragma unroll
        for (int r = 0; r < 8; ++r) {
          float4 sv = *(const float4*)(gs + r*128 + c4*4);   // uniform
          acc[r] += sv.x*w0 + sv.y*w1 + sv.z*w2 + sv.w*w3;
        }
      }
      #pragma unroll
      for (int c4 = 0; c4 < 4; ++c4) {           // tail c in [128,144)
        const float w0 = W_av[(128 + c4*4+0)*64 + lane];
        const float w1 = W_av[(128 + c4*4+1)*64 + lane];
        const float w2 = W_av[(128 + c4*4+2)*64 + lane];
        const float w3 = W_av[(128 + c4*4+3)*64 + lane];
        #pragma unroll
        for (int r = 0; r < 8; ++r) {
          float4 sv = *(const float4*)(gt + r*16 + c4*4);
          acc[r] += sv.x*w0 + sv.y*w1 + sv.z*w2 + sv.w*w3;
        }
      }
      #pragma unroll
      for (int r = 0; r < 8; ++r)
        s_pre[(sub + r)*132 + ap*64 + lane] = acc[r];
    }
    __syncthreads();
    {
      // combine: avA = tanh(preA) -> ws ; delta = tanh(preP) - avA -> LDS
      const int r = t >> 4, d0 = (t & 15) << 2;
      float4 a0 = *(const float4*)(s_pre + r*132 + d0);
      float4 p0 = *(const float4*)(s_pre + r*132 + 64 + d0);
      float4 va, dl;
      va.x = tanhf(a0.x); va.y = tanhf(a0.y); va.z = tanhf(a0.z); va.w = tanhf(a0.w);
      dl.x = tanhf(p0.x) - va.x; dl.y = tanhf(p0.y) - va.y;
      dl.z = tanhf(p0.z) - va.z; dl.w = tanhf(p0.w) - va.w;
      *(float4*)(ws + WS_AVA + b*2048 + (k0 + r)*64 + d0) = va;
      *(float4*)(s_dl + r*68 + d0) = dl;
    }
    __syncthreads();
    {
      // dproj[j][h] = sum_d delta[j][d] * W_f1a[d][h]; wave rg: 4 rows
      const int q0 = rg << 2;
      float acc[4] = {0,0,0,0};
      #pragma unroll 4
      for (int d4 = 0; d4 < 16; ++d4) {
        const float w0 = W_f1[(d4*4+0)*64 + lane];
        const float w1 = W_f1[(d4*4+1)*64 + lane];
        const float w2 = W_f1[(d4*4+2)*64 + lane];
        const float w3 = W_f1[(d4*4+3)*64 + lane];
        #pragma unroll
        for (int q = 0; q < 4; ++q) {
          float4 dv = *(const float4*)(s_dl + (q0+q)*68 + d4*4);  // uniform
          acc[q] += dv.x*w0 + dv.y*w1 + dv.z*w2 + dv.w*w3;
        }
      }
      #pragma unroll
      for (int q = 0; q < 4; ++q)
        ws[WS_DPROJ + b*2048 + (k0 + q0 + q)*64 + lane] = acc[q];
    }
    return;
  }
  blk -= 256;

  // ---- per (b, 16-row quarter): avO -> ws (no LDS) -----------------------
  {
    const int b = blk >> 2, m0 = (blk & 3) << 4;
    const int rg = t >> 6, lane = t & 63;
    const float* gso = g_so + (b*64 + m0 + rg*4) * 128;
    const float* gao = g_ao + (b*64 + m0 + rg*4) * 16;
    float acc[4] = {0,0,0,0};
    #pragma unroll 4
    for (int c4 = 0; c4 < 32; ++c4) {
      const float w0 = W_avo[(c4*4+0)*64 + lane];
      const float w1 = W_avo[(c4*4+1)*64 + lane];
      const float w2 = W_avo[(c4*4+2)*64 + lane];
      const float w3 = W_avo[(c4*4+3)*64 + lane];
      #pragma unroll
      for (int r = 0; r < 4; ++r) {
        float4 sv = *(const float4*)(gso + r*128 + c4*4);    // uniform
        acc[r] += sv.x*w0 + sv.y*w1 + sv.z*w2 + sv.w*w3;
      }
    }
    #pragma unroll
    for (int c4 = 0; c4 < 4; ++c4) {
      const float w0 = W_avo[(128 + c4*4+0)*64 + lane];
      const float w1 = W_avo[(128 + c4*4+1)*64 + lane];
      const float w2 = W_avo[(128 + c4*4+2)*64 + lane];
      const float w3 = W_avo[(128 + c4*4+3)*64 + lane];
      #pragma unroll
      for (int r = 0; r < 4; ++r) {
        float4 sv = *(const float4*)(gao + r*16 + c4*4);
        acc[r] += sv.x*w0 + sv.y*w1 + sv.z*w2 + sv.w*w3;
      }
    }
    #pragma unroll
    for (int r = 0; r < 4; ++r)
      ws[WS_AVO + b*4096 + (m0 + rg*4 + r)*64 + lane] = tanhf(acc[r]);
  }
}

// ---------------------------------------------------------------------------
// K2: main, per (b, i-octile). grid 512. LDS 13376 floats = 52.25 KB (3/CU).
// Identical to R8.
// ---------------------------------------------------------------------------
__global__ __launch_bounds__(256) void k2_main(
    const float* __restrict__ g_states, const float* __restrict__ g_so,
    const float* __restrict__ W_f1, const float* __restrict__ W_f2,
    const float* __restrict__ ws, float* __restrict__ out)
{
  __shared__ __align__(16) float pool[13376];
  float* s_st   = pool;
  float* s_avO  = pool;            // alias A (after so tiles done)
  float* s_avA  = pool + 4352;
  float* s_dp   = pool + 6528;
  float* s_P    = pool + 8704;
  float* s_w    = pool + 10848;
  float* s_wo   = pool + 11136;
  float* s_S    = pool + 11680;
  float* s_wavo = pool + 12224;
  float* s_base = pool + 12768;
  float* s_wf2  = pool + 13312;

  const int t = threadIdx.x;
  const int b = blockIdx.x >> 2;
  const int i0 = (blockIdx.x & 3) << 3;

  // ---- ph1: stage states (for ph3 j-side), avA, dproj, wf2 ---------------
  {
    const float4* gs4 = (const float4*)(g_states + b * 4096);
    #pragma unroll
    for (int u = 0; u < 4; ++u) {
      int f = t + u * 256;
      int r = f >> 5, c4 = f & 31;
      *(float4*)(s_st + r*132 + c4*4) = gs4[f];
    }
    #pragma unroll
    for (int u = 0; u < 2; ++u) {
      int f = t + u * 256;                  // 0..511 float4
      int k = f >> 4, dq = f & 15;
      *(float4*)(s_avA + k*68 + dq*4) = ((const float4*)(ws + WS_AVA + b*2048))[f];
      *(float4*)(s_dp  + k*68 + dq*4) = ((const float4*)(ws + WS_DPROJ + b*2048))[f];
    }
    if (t < 16) *(float4*)(s_wf2 + t*4) = ((const float4*)W_f2)[t];
  }

  // ---- ph2: P = states[i0..+8] @ [Wqk|Wqko], register-resident row-split -
  {
    const int wv = t >> 6, lane = t & 63;
    const int r0 = wv * 2;
    const float* Wbase = (lane < 32) ? (ws + WS_WQK  + lane*4)
                                     : (ws + WS_WQKO + (lane-32)*4);
    const float* srow0 = g_states + b*4096 + (i0 + r0)*128;
    const float* srow1 = srow0 + 128;
    float4 a0 = {0,0,0,0}, a1 = {0,0,0,0};
    #pragma unroll 4
    for (int c4 = 0; c4 < 32; ++c4) {
      float4 s0 = *(const float4*)(srow0 + c4*4);   // uniform
      float4 s1 = *(const float4*)(srow1 + c4*4);
      #pragma unroll
      for (int kk = 0; kk < 4; ++kk) {
        float4 wv4 = *(const float4*)(Wbase + (c4*4 + kk)*128);  // coalesced
        fma4(a0, wv4, ((const float*)&s0)[kk]);
        fma4(a1, wv4, ((const float*)&s1)[kk]);
      }
    }
    *(float4*)(s_P + r0*268 + lane*4)       = a0;
    *(float4*)(s_P + (r0+1)*268 + lane*4)   = a1;
  }
  __syncthreads();

  // ---- ph3: self scores + register softmax + write ret_weight ------------
  {
    const int r = t >> 5, j = t & 31;
    float acc = 0.f;
    #pragma unroll 8
    for (int e4 = 0; e4 < 32; ++e4) {
      float4 p4  = *(const float4*)(s_P + r*268 + e4*4);
      float4 st4 = *(const float4*)(s_st + j*132 + e4*4);
      acc += dot4(p4, st4);
    }
    acc *= INV_SQRT_DK;
    float mx = acc;
    for (int off = 16; off; off >>= 1) mx = fmaxf(mx, __shfl_xor(mx, off, 32));
    float ev = __expf(acc - mx);
    float sum = ev;
    for (int off = 16; off; off >>= 1) sum += __shfl_xor(sum, off, 32);
    float wn = ev / sum;
    out[131072 + b*1024 + (i0 + r)*32 + j] = wn;
    s_w[r*36 + j] = wn;
  }
  __syncthreads();

  // ---- ph4/5: other scores over two states_other tiles -------------------
  for (int tt = 0; tt < 2; ++tt) {
    const float4* gt4 = (const float4*)(g_so + (b*64 + tt*32) * 128);
    #pragma unroll
    for (int u = 0; u < 4; ++u) {
      int f = t + u * 256;
      int r = f >> 5, c4 = f & 31;
      *(float4*)(s_st + r*132 + c4*4) = gt4[f];
    }
    __syncthreads();
    const int r = t >> 5, m = t & 31;
    float acc = 0.f;
    #pragma unroll 8
    for (int c4 = 0; c4 < 32; ++c4) {
      float4 p4  = *(const float4*)(s_P + r*268 + 128 + c4*4);
      float4 st4 = *(const float4*)(s_st + m*132 + c4*4);
      acc += dot4(p4, st4);
    }
    s_wo[r*68 + tt*32 + m] = acc * INV_SQRT_DK;
    __syncthreads();
  }

  // ---- ph6: softmax wo + write weight_other; stage avO -------------------
  #pragma unroll
  for (int p = 0; p < 2; ++p) {
    const int r = (t >> 6) + (p << 2), l = t & 63;
    float v = s_wo[r*68 + l];
    float mx = v;
    for (int off = 32; off; off >>= 1) mx = fmaxf(mx, __shfl_xor(mx, off, 64));
    float ev = __expf(v - mx);
    float sum = ev;
    for (int off = 32; off; off >>= 1) sum += __shfl_xor(sum, off, 64);
    float wn = ev / sum;
    out[262144 + b*2048 + (i0 + r)*64 + l] = wn;
    s_wo[r*68 + l] = wn;
  }
  #pragma unroll
  for (int u = 0; u < 4; ++u) {
    int f = t + u * 256;
    int m = f >> 4, dq = f & 15;
    *(float4*)(s_avO + m*68 + dq*4) = ((const float4*)(ws + WS_AVO + b*4096))[f];
  }
  __syncthreads();

  // ---- ph7: S = w @ avA (t<128); wavo = wo @ avO (t>=128) ----------------
  if (t < 128) {
    const int i = t >> 4, dq = (t & 15) << 2;
    float4 acc = {0,0,0,0};
    #pragma unroll 4
    for (int k = 0; k < 32; ++k) {
      float4 a4 = *(const float4*)(s_avA + k*68 + dq);
      float wv = s_w[i*36 + k];
      acc.x += wv*a4.x; acc.y += wv*a4.y; acc.z += wv*a4.z; acc.w += wv*a4.w;
    }
    *(float4*)(s_S + i*68 + dq) = acc;
  } else {
    const int tt2 = t - 128;
    const int i = tt2 >> 4, dq = (tt2 & 15) << 2;
    float4 acc = {0,0,0,0};
    #pragma unroll 4
    for (int m = 0; m < 64; ++m) {
      float4 a4 = *(const float4*)(s_avO + m*68 + dq);
      float wv = s_wo[i*68 + m];
      acc.x += wv*a4.x; acc.y += wv*a4.y; acc.z += wv*a4.z; acc.w += wv*a4.w;
    }
    *(float4*)(s_wavo + i*68 + dq) = acc;
  }
  __syncthreads();

  // ---- ph8: base = S@Wf1a + wavo@Wf1b ------------------------------------
  {
    const int h = t & 63, g = (t >> 6) << 1;
    float a0 = 0.f, a1 = 0.f;
    #pragma unroll 4
    for (int d = 0; d < 64; ++d) {
      float w1v = W_f1[d*64 + h];
      float w2v = W_f1[(64 + d)*64 + h];
      a0 += s_S[g*68 + d]*w1v + s_wavo[g*68 + d]*w2v;
      a1 += s_S[(g+1)*68 + d]*w1v + s_wavo[(g+1)*68 + d]*w2v;
    }
    s_base[g*68 + h] = a0;
    s_base[(g+1)*68 + h] = a1;
  }
  __syncthreads();

  // ---- ph9: value[i][j] = sum_h lrelu(base[i,h]+w[i,j]*dproj[j,h])*Wf2[h] -
  {
    const int i = t >> 5, j = t & 31;
    const float wij = s_w[i*36 + j];
    float acc = 0.f;
    #pragma unroll 4
    for (int hq = 0; hq < 16; ++hq) {
      float4 b4 = *(const float4*)(s_base + i*68 + hq*4);
      float4 d4 = *(const float4*)(s_dp + j*68 + hq*4);
      float4 f4 = *(const float4*)(s_wf2 + hq*4);
      float p0 = b4.x + wij*d4.x; p0 = p0 > 0.f ? p0 : 0.01f*p0;
      float p1 = b4.y + wij*d4.y; p1 = p1 > 0.f ? p1 : 0.01f*p1;
      float p2 = b4.z + wij*d4.z; p2 = p2 > 0.f ? p2 : 0.01f*p2;
      float p3 = b4.w + wij*d4.w; p3 = p3 > 0.f ? p3 : 0.01f*p3;
      acc += p0*f4.x + p1*f4.y + p2*f4.z + p3*f4.w;
    }
    out[b*1024 + (i0 + i)*32 + j] = acc;
  }
}

extern "C" void kernel_launch(void* const* d_in, const int* in_sizes, int n_in,
                              void* d_out, int out_size, void* d_ws, size_t ws_size,
                              hipStream_t stream) {
  const float* states        = (const float*)d_in[0];
  const float* policies      = (const float*)d_in[1];
  const float* actions       = (const float*)d_in[2];
  const float* states_other  = (const float*)d_in[3];
  const float* actions_other = (const float*)d_in[4];
  const float* W_key         = (const float*)d_in[5];
  const float* W_query       = (const float*)d_in[6];
  const float* W_av          = (const float*)d_in[7];
  const float* W_key_other   = (const float*)d_in[8];
  const float* W_query_other = (const float*)d_in[9];
  const float* W_av_other    = (const float*)d_in[10];
  const float* W_f1          = (const float*)d_in[11];
  const float* W_f2          = (const float*)d_in[12];
  float* out = (float*)d_out;
  float* ws  = (float*)d_ws;   // 4.125 MB used

  k1_pre<<<800, 256, 0, stream>>>(states, policies, actions, states_other,
                                  actions_other, W_query, W_key,
                                  W_query_other, W_key_other, W_av, W_av_other,
                                  W_f1, ws);
  k2_main<<<512, 256, 0, stream>>>(states, states_other, W_f1, W_f2, ws, out);
}